// Round 1
// baseline (798.289 us; speedup 1.0000x reference)
//
#include <hip/hip_runtime.h>
#include <hip/hip_bf16.h>

// Problem constants (from reference)
#define IN_DIM 256
#define HID    128
#define NSEG   320          // BATCH * MAX_COM = 32 * 10
#define MAXNORM 0.99999     // (1 - 1e-5)/sqrt(c), c=1

// ---------------------------------------------------------------------------
// CSR build: count -> exclusive scan -> fill (reused for both GCN layers)
// ---------------------------------------------------------------------------
__global__ void count_edges_k(const int* __restrict__ dst, int* __restrict__ counts, int n) {
    int e = blockIdx.x * 256 + threadIdx.x;
    if (e < n) atomicAdd(&counts[dst[e]], 1);
}

// 1024 elements per block, 256 threads, int4 per thread
__global__ void scan_block_k(const int* __restrict__ in, int* __restrict__ out,
                             int* __restrict__ partials) {
    __shared__ int sh[256];
    int tid = threadIdx.x;
    int base = blockIdx.x * 1024 + tid * 4;
    int4 v = *(const int4*)&in[base];
    int s = v.x + v.y + v.z + v.w;
    sh[tid] = s;
    __syncthreads();
#pragma unroll
    for (int off = 1; off < 256; off <<= 1) {
        int t = (tid >= off) ? sh[tid - off] : 0;
        __syncthreads();
        sh[tid] += t;
        __syncthreads();
    }
    int excl = sh[tid] - s;
    int4 o;
    o.x = excl; o.y = excl + v.x; o.z = o.y + v.y; o.w = o.z + v.z;
    *(int4*)&out[base] = o;
    if (tid == 255) partials[blockIdx.x] = sh[255];
}

// exclusive scan of `n<=1024` partials in-place, single block of n threads
__global__ void scan_partials_k(int* __restrict__ partials, int n) {
    __shared__ int sh[1024];
    int tid = threadIdx.x;
    int v = (tid < n) ? partials[tid] : 0;
    sh[tid] = v;
    __syncthreads();
    for (int off = 1; off < blockDim.x; off <<= 1) {
        int t = (tid >= off) ? sh[tid - off] : 0;
        __syncthreads();
        sh[tid] += t;
        __syncthreads();
    }
    if (tid < n) partials[tid] = sh[tid] - v;
}

__global__ void add_base_k(int* __restrict__ offsets, const int* __restrict__ partials, int n) {
    int g = blockIdx.x * 256 + threadIdx.x;
    if (g < n) offsets[g] += partials[g >> 10];
}

__global__ void fill_edges_k(const int* __restrict__ src, const int* __restrict__ dst,
                             const int* __restrict__ offsets, int* __restrict__ cursor,
                             int* __restrict__ sorted_src, int n) {
    int e = blockIdx.x * 256 + threadIdx.x;
    if (e < n) {
        int d = dst[e];
        int pos = atomicAdd(&cursor[d], 1);
        sorted_src[offsets[d] + pos] = src[e];
    }
}

// ---------------------------------------------------------------------------
// fp32 GEMM: C[M][128] = A[M][K] @ B[K][128], K in {256,128}, M % 64 == 0
// 256 threads, BM=64, BN=128, BK=64; per-thread 4x8 register tile
// ---------------------------------------------------------------------------
__global__ __launch_bounds__(256) void gemm_nn_k(const float* __restrict__ A,
                                                 const float* __restrict__ B,
                                                 float* __restrict__ C, int K) {
    __shared__ float As[64][64];    // 16 KB
    __shared__ float Bs[64][128];   // 32 KB
    const int tid = threadIdx.x;
    const int row0 = blockIdx.x * 64;
    const int tr = tid >> 4;   // 0..15, rows tr*4+i
    const int tc = tid & 15;   // 0..15, cols tc*8+j
    float acc[4][8] = {};

    for (int k0 = 0; k0 < K; k0 += 64) {
        {   // stage A tile: 64x64 floats, 4 float4 per thread
            int r = tid >> 4;
            int cg = (tid & 15) * 4;
#pragma unroll
            for (int rr = 0; rr < 64; rr += 16) {
                float4 v = *(const float4*)&A[(size_t)(row0 + r + rr) * K + k0 + cg];
                *(float4*)&As[r + rr][cg] = v;
            }
        }
        {   // stage B tile: 64x128 floats, 8 float4 per thread
            int r = tid >> 5;
            int cg = (tid & 31) * 4;
#pragma unroll
            for (int rr = 0; rr < 64; rr += 8) {
                float4 v = *(const float4*)&B[(size_t)(k0 + r + rr) * 128 + cg];
                *(float4*)&Bs[r + rr][cg] = v;
            }
        }
        __syncthreads();
#pragma unroll
        for (int kk = 0; kk < 64; ++kk) {
            float a[4];
#pragma unroll
            for (int i = 0; i < 4; ++i) a[i] = As[tr * 4 + i][kk];
            float4 b0 = *(const float4*)&Bs[kk][tc * 8];
            float4 b1 = *(const float4*)&Bs[kk][tc * 8 + 4];
            float b[8] = {b0.x, b0.y, b0.z, b0.w, b1.x, b1.y, b1.z, b1.w};
#pragma unroll
            for (int i = 0; i < 4; ++i)
#pragma unroll
                for (int j = 0; j < 8; ++j)
                    acc[i][j] = fmaf(a[i], b[j], acc[i][j]);
        }
        __syncthreads();
    }
#pragma unroll
    for (int i = 0; i < 4; ++i) {
        float4 o0 = {acc[i][0], acc[i][1], acc[i][2], acc[i][3]};
        float4 o1 = {acc[i][4], acc[i][5], acc[i][6], acc[i][7]};
        size_t base = (size_t)(row0 + tr * 4 + i) * 128 + tc * 8;
        *(float4*)&C[base] = o0;
        *(float4*)&C[base + 4] = o1;
    }
}

// ---------------------------------------------------------------------------
// Pull-gather over in-edges + bias + tanh. One wave per node, 2 dims per lane.
// ---------------------------------------------------------------------------
__global__ __launch_bounds__(256) void gather_bias_tanh_k(
    const float* __restrict__ sup, const int* __restrict__ offsets,
    const int* __restrict__ counts, const int* __restrict__ ssrc,
    const float* __restrict__ bias, float* __restrict__ out, int n_nodes) {
    int node = (blockIdx.x << 2) | (threadIdx.x >> 6);
    if (node >= n_nodes) return;
    int lane = threadIdx.x & 63;
    int off = offsets[node];
    int cnt = counts[node];
    float ax = bias[2 * lane], ay = bias[2 * lane + 1];
    int i = 0;
    for (; i + 4 <= cnt; i += 4) {
        int s0 = ssrc[off + i + 0], s1 = ssrc[off + i + 1];
        int s2 = ssrc[off + i + 2], s3 = ssrc[off + i + 3];
        float2 v0 = *(const float2*)&sup[(size_t)s0 * 128 + 2 * lane];
        float2 v1 = *(const float2*)&sup[(size_t)s1 * 128 + 2 * lane];
        float2 v2 = *(const float2*)&sup[(size_t)s2 * 128 + 2 * lane];
        float2 v3 = *(const float2*)&sup[(size_t)s3 * 128 + 2 * lane];
        ax += v0.x + v1.x + v2.x + v3.x;
        ay += v0.y + v1.y + v2.y + v3.y;
    }
    for (; i < cnt; ++i) {
        int s = ssrc[off + i];
        float2 v = *(const float2*)&sup[(size_t)s * 128 + 2 * lane];
        ax += v.x; ay += v.y;
    }
    float2 r;
    r.x = tanhf(ax);
    r.y = tanhf(ay);
    *(float2*)&out[(size_t)node * 128 + 2 * lane] = r;
}

// ---------------------------------------------------------------------------
// Layer-2 gather + bias + tanh + (proj∘logmap0 analytic) + segment-sum pool
// ---------------------------------------------------------------------------
__global__ __launch_bounds__(256) void gather_pool_k(
    const float* __restrict__ sup, const int* __restrict__ offsets,
    const int* __restrict__ counts, const int* __restrict__ ssrc,
    const float* __restrict__ bias, const int* __restrict__ seg_ids,
    float* __restrict__ sums, int* __restrict__ seg_cnt, int n_nodes) {
    int node = (blockIdx.x << 2) | (threadIdx.x >> 6);
    if (node >= n_nodes) return;
    int lane = threadIdx.x & 63;
    int off = offsets[node];
    int cnt = counts[node];
    float ax = bias[2 * lane], ay = bias[2 * lane + 1];
    int i = 0;
    for (; i + 4 <= cnt; i += 4) {
        int s0 = ssrc[off + i + 0], s1 = ssrc[off + i + 1];
        int s2 = ssrc[off + i + 2], s3 = ssrc[off + i + 3];
        float2 v0 = *(const float2*)&sup[(size_t)s0 * 128 + 2 * lane];
        float2 v1 = *(const float2*)&sup[(size_t)s1 * 128 + 2 * lane];
        float2 v2 = *(const float2*)&sup[(size_t)s2 * 128 + 2 * lane];
        float2 v3 = *(const float2*)&sup[(size_t)s3 * 128 + 2 * lane];
        ax += v0.x + v1.x + v2.x + v3.x;
        ay += v0.y + v1.y + v2.y + v3.y;
    }
    for (; i < cnt; ++i) {
        int s = ssrc[off + i];
        float2 v = *(const float2*)&sup[(size_t)s * 128 + 2 * lane];
        ax += v.x; ay += v.y;
    }
    float hx = tanhf(ax), hy = tanhf(ay);
    // row norm over 128 dims (2 per lane, 64 lanes)
    float ss = hx * hx + hy * hy;
#pragma unroll
    for (int o = 32; o > 0; o >>= 1) ss += __shfl_xor(ss, o);
    // y = h * atanh(min(r, maxnorm)) / r   ==  logmap0(proj(h))
    double r = sqrt((double)fmaxf(ss, 1e-15f));
    double m = fmin(r, MAXNORM);
    float f = (float)(atanh(m) / r);
    int seg = seg_ids[node];
    atomicAdd(&sums[seg * 128 + 2 * lane], hx * f);
    atomicAdd(&sums[seg * 128 + 2 * lane + 1], hy * f);
    if (lane == 0) atomicAdd(&seg_cnt[seg], 1);
}

// ---------------------------------------------------------------------------
// Segment mean -> expmap0 -> proj. One wave per segment.
// ---------------------------------------------------------------------------
__global__ __launch_bounds__(64) void finalize_k(const float* __restrict__ sums,
                                                 const int* __restrict__ seg_cnt,
                                                 float* __restrict__ out) {
    int seg = blockIdx.x;
    int lane = threadIdx.x;
    float c = fmaxf((float)seg_cnt[seg], 1.0f);
    float ux = sums[seg * 128 + 2 * lane] / c;
    float uy = sums[seg * 128 + 2 * lane + 1] / c;
    float ss = ux * ux + uy * uy;
#pragma unroll
    for (int o = 32; o > 0; o >>= 1) ss += __shfl_xor(ss, o);
    double r = sqrt((double)fmaxf(ss, 1e-15f));
    double t = tanh(r);
    double fac = t / r;                       // expmap0 scale
    if (t > MAXNORM) fac = MAXNORM / r;       // proj clip (result norm = tanh(r))
    float f = (float)fac;
    out[seg * 128 + 2 * lane] = ux * f;
    out[seg * 128 + 2 * lane + 1] = uy * f;
}

// ---------------------------------------------------------------------------
extern "C" void kernel_launch(void* const* d_in, const int* in_sizes, int n_in,
                              void* d_out, int out_size, void* d_ws, size_t ws_size,
                              hipStream_t stream) {
    const float* x   = (const float*)d_in[0];
    const int* src   = (const int*)d_in[1];
    const int* dst   = (const int*)d_in[2];
    const int* segid = (const int*)d_in[3];
    const float* W1  = (const float*)d_in[4];
    const float* b1  = (const float*)d_in[5];
    const float* W2  = (const float*)d_in[6];
    const float* b2  = (const float*)d_in[7];
    float* out       = (float*)d_out;

    const int N = in_sizes[3];          // 131072 nodes
    const int E = in_sizes[1];          // 2097152 edges

    // workspace layout (all 256B-aligned)
    char* ws = (char*)d_ws;
    float* bufA    = (float*)(ws);                       // N*128 f32 = 64MB
    float* bufB    = (float*)(ws + 67108864);            // N*128 f32 = 64MB
    int* counts    = (int*)(ws + 134217728);             // N ints
    int* offsets   = (int*)(ws + 134742016);             // N ints
    int* cursor    = (int*)(ws + 135266304);             // N ints
    int* partials  = (int*)(ws + 135790592);             // 1KB
    int* ssrc      = (int*)(ws + 135791616);             // E ints = 8MB
    float* sums    = (float*)(ws + 144180224);           // NSEG*128 f32
    int* seg_cnt   = (int*)(ws + 144344064);             // NSEG ints

    // zero state consumed via atomics (poisoned 0xAA otherwise)
    hipMemsetAsync(counts, 0, (size_t)N * 4, stream);
    hipMemsetAsync(cursor, 0, (size_t)N * 4, stream);
    hipMemsetAsync(sums, 0, (size_t)NSEG * 128 * 4, stream);
    hipMemsetAsync(seg_cnt, 0, (size_t)NSEG * 4, stream);

    const int eblocks = (E + 255) / 256;
    const int nscan = N / 1024;                 // 128 blocks of 1024

    // CSR build (reused by both layers)
    count_edges_k<<<eblocks, 256, 0, stream>>>(dst, counts, E);
    scan_block_k<<<nscan, 256, 0, stream>>>(counts, offsets, partials);
    scan_partials_k<<<1, nscan, 0, stream>>>(partials, nscan);
    add_base_k<<<(N + 255) / 256, 256, 0, stream>>>(offsets, partials, N);
    fill_edges_k<<<eblocks, 256, 0, stream>>>(src, dst, offsets, cursor, ssrc, E);

    // layer 1: support = x @ W1 ; h1 = tanh(gather + b1)
    gemm_nn_k<<<N / 64, 256, 0, stream>>>(x, W1, bufA, IN_DIM);
    gather_bias_tanh_k<<<N / 4, 256, 0, stream>>>(bufA, offsets, counts, ssrc, b1, bufB, N);

    // layer 2: support = h1 @ W2 ; fused gather + tanh + logmap0∘proj + pool
    gemm_nn_k<<<N / 64, 256, 0, stream>>>(bufB, W2, bufA, HID);
    gather_pool_k<<<N / 4, 256, 0, stream>>>(bufA, offsets, counts, ssrc, b2, segid,
                                             sums, seg_cnt, N);

    // segment mean -> expmap0 -> proj
    finalize_k<<<NSEG, 64, 0, stream>>>(sums, seg_cnt, out);
}

// Round 2
// 602.565 us; speedup vs baseline: 1.3248x; 1.3248x over previous
//
#include <hip/hip_runtime.h>
#include <hip/hip_bf16.h>

#define IN_DIM 256
#define HID    128
#define NSEG   320
#define MAXNORM 0.99999

typedef short bf16x8 __attribute__((ext_vector_type(8)));
typedef float f32x4  __attribute__((ext_vector_type(4)));

static __device__ __forceinline__ ushort f2b(float f) {
    uint u = __builtin_bit_cast(uint, f);
    uint r = 0x7FFFu + ((u >> 16) & 1u);      // round-to-nearest-even
    return (ushort)((u + r) >> 16);
}
static __device__ __forceinline__ float b2f_lo(uint v) {
    return __builtin_bit_cast(float, v << 16);
}
static __device__ __forceinline__ float b2f_hi(uint v) {
    return __builtin_bit_cast(float, v & 0xFFFF0000u);
}

// ---------------------------------------------------------------------------
// CSR build: count -> exclusive scan -> fill (reused for both GCN layers)
// ---------------------------------------------------------------------------
__global__ void count_edges_k(const int* __restrict__ dst, int* __restrict__ counts, int n) {
    int e = blockIdx.x * 256 + threadIdx.x;
    if (e < n) atomicAdd(&counts[dst[e]], 1);
}

__global__ void scan_block_k(const int* __restrict__ in, int* __restrict__ out,
                             int* __restrict__ partials) {
    __shared__ int sh[256];
    int tid = threadIdx.x;
    int base = blockIdx.x * 1024 + tid * 4;
    int4 v = *(const int4*)&in[base];
    int s = v.x + v.y + v.z + v.w;
    sh[tid] = s;
    __syncthreads();
#pragma unroll
    for (int off = 1; off < 256; off <<= 1) {
        int t = (tid >= off) ? sh[tid - off] : 0;
        __syncthreads();
        sh[tid] += t;
        __syncthreads();
    }
    int excl = sh[tid] - s;
    int4 o;
    o.x = excl; o.y = excl + v.x; o.z = o.y + v.y; o.w = o.z + v.z;
    *(int4*)&out[base] = o;
    if (tid == 255) partials[blockIdx.x] = sh[255];
}

__global__ void scan_partials_k(int* __restrict__ partials, int n) {
    __shared__ int sh[1024];
    int tid = threadIdx.x;
    int v = (tid < n) ? partials[tid] : 0;
    sh[tid] = v;
    __syncthreads();
    for (int off = 1; off < blockDim.x; off <<= 1) {
        int t = (tid >= off) ? sh[tid - off] : 0;
        __syncthreads();
        sh[tid] += t;
        __syncthreads();
    }
    if (tid < n) partials[tid] = sh[tid] - v;
}

__global__ void add_base_k(int* __restrict__ offsets, const int* __restrict__ partials, int n) {
    int g = blockIdx.x * 256 + threadIdx.x;
    if (g < n) offsets[g] += partials[g >> 10];
}

__global__ void fill_edges_k(const int* __restrict__ src, const int* __restrict__ dst,
                             const int* __restrict__ offsets, int* __restrict__ cursor,
                             int* __restrict__ sorted_src, int n) {
    int e = blockIdx.x * 256 + threadIdx.x;
    if (e < n) {
        int d = dst[e];
        int pos = atomicAdd(&cursor[d], 1);
        sorted_src[offsets[d] + pos] = src[e];
    }
}

// ---------------------------------------------------------------------------
// W pre-transpose+convert: W[K][128] f32 -> WT[128][K] bf16 (both weights)
// ---------------------------------------------------------------------------
__global__ void prep_wt_k(const float* __restrict__ w1, const float* __restrict__ w2,
                          ushort* __restrict__ w1t, ushort* __restrict__ w2t) {
    int id = blockIdx.x * 256 + threadIdx.x;
    if (id < 32768) {                      // W1: 256x128 -> 128x256
        int n = id >> 8, k = id & 255;
        w1t[n * 256 + k] = f2b(w1[k * 128 + n]);
    } else {                               // W2: 128x128 -> 128x128
        int id2 = id - 32768;
        int n = id2 >> 7, k = id2 & 127;
        w2t[n * 128 + k] = f2b(w2[k * 128 + n]);
    }
}

// ---------------------------------------------------------------------------
// bf16 MFMA GEMM: C[M][128](bf16) = A[M][K] @ B[K][128]
// A: f32 (AF32=true) or bf16; B passed pre-transposed BT[128][K] bf16.
// Block: 128x128 tile, 256 thr = 4 waves (2x2), BK=64, 16x16x32 MFMA.
// LDS XOR-swizzle ((row&7)<<4) on byte offsets -> ~2-way max on ds_read_b128.
// ---------------------------------------------------------------------------
template<bool AF32>
__global__ __launch_bounds__(256) void gemm_k(const void* __restrict__ Ap,
                                              const ushort* __restrict__ BT,
                                              ushort* __restrict__ C, int K) {
    __shared__ __align__(16) char As[16384];   // [128][64] bf16, swizzled
    __shared__ __align__(16) char Bs[16384];   // [128(n)][64(k)] bf16, swizzled
    const int tid = threadIdx.x;
    const int lane = tid & 63;
    const int wid = tid >> 6;
    const int wr = wid >> 1, wc = wid & 1;
    const int row0 = blockIdx.x * 128;
    f32x4 acc[4][4] = {};

    for (int k0 = 0; k0 < K; k0 += 64) {
        if (AF32) {
            const float* A = (const float*)Ap;
#pragma unroll
            for (int it = 0; it < 8; ++it) {    // 2048 float4 = 128 rows x 16
                int id = tid + it * 256;
                int r = id >> 4, c4 = (id & 15) * 4;
                float4 v = *(const float4*)&A[(size_t)(row0 + r) * K + k0 + c4];
                ushort4 h;
                h.x = f2b(v.x); h.y = f2b(v.y); h.z = f2b(v.z); h.w = f2b(v.w);
                *(ushort4*)(As + ((r * 128 + c4 * 2) ^ ((r & 7) << 4))) = h;
            }
        } else {
            const ushort* A = (const ushort*)Ap;
#pragma unroll
            for (int it = 0; it < 4; ++it) {    // 1024 16B = 128 rows x 8
                int id = tid + it * 256;
                int r = id >> 3, c8 = (id & 7) * 8;
                bf16x8 v = *(const bf16x8*)&A[(size_t)(row0 + r) * K + k0 + c8];
                *(bf16x8*)(As + ((r * 128 + c8 * 2) ^ ((r & 7) << 4))) = v;
            }
        }
#pragma unroll
        for (int it = 0; it < 4; ++it) {        // B tile: 128 n-rows x 64 k
            int id = tid + it * 256;
            int n = id >> 3, c8 = (id & 7) * 8;
            bf16x8 v = *(const bf16x8*)&BT[(size_t)n * K + k0 + c8];
            *(bf16x8*)(Bs + ((n * 128 + c8 * 2) ^ ((n & 7) << 4))) = v;
        }
        __syncthreads();
#pragma unroll
        for (int kc = 0; kc < 2; ++kc) {
            bf16x8 af[4], bfr[4];
            int kb = (kc * 32 + (lane >> 4) * 8) * 2;
#pragma unroll
            for (int i = 0; i < 4; ++i) {
                int r = wr * 64 + i * 16 + (lane & 15);
                af[i] = *(const bf16x8*)(As + ((r * 128 + kb) ^ ((r & 7) << 4)));
                int n = wc * 64 + i * 16 + (lane & 15);
                bfr[i] = *(const bf16x8*)(Bs + ((n * 128 + kb) ^ ((n & 7) << 4)));
            }
#pragma unroll
            for (int i = 0; i < 4; ++i)
#pragma unroll
                for (int j = 0; j < 4; ++j)
                    acc[i][j] = __builtin_amdgcn_mfma_f32_16x16x32_bf16(
                        af[i], bfr[j], acc[i][j], 0, 0, 0);
        }
        __syncthreads();
    }
    // epilogue: C/D layout col=lane&15, row=(lane>>4)*4+reg  [m89]
#pragma unroll
    for (int i = 0; i < 4; ++i)
#pragma unroll
        for (int j = 0; j < 4; ++j)
#pragma unroll
            for (int r = 0; r < 4; ++r) {
                int row = row0 + wr * 64 + i * 16 + (lane >> 4) * 4 + r;
                int col = wc * 64 + j * 16 + (lane & 15);
                C[(size_t)row * 128 + col] = f2b(acc[i][j][r]);
            }
}

// ---------------------------------------------------------------------------
// Gather core: wave-parallel index preload + 8-deep unrolled row loads.
// Support rows are 128 bf16 = 64 uints; lane owns dims {2*lane, 2*lane+1}.
// ---------------------------------------------------------------------------
static __device__ __forceinline__ void gather_node(
    const uint* __restrict__ sup, const int* __restrict__ offsets,
    const int* __restrict__ counts, const int* __restrict__ ssrc,
    const float* __restrict__ bias, int node, int lane, float& ax, float& ay) {
    int off = offsets[node];
    int cnt = counts[node];
    ax = bias[2 * lane];
    ay = bias[2 * lane + 1];
    int n0 = min(cnt, 64);
    int my = 0;
    if (lane < n0) my = ssrc[off + lane];
    int j = 0;
    for (; j + 8 <= n0; j += 8) {
        int s0 = __shfl(my, j + 0), s1 = __shfl(my, j + 1);
        int s2 = __shfl(my, j + 2), s3 = __shfl(my, j + 3);
        int s4 = __shfl(my, j + 4), s5 = __shfl(my, j + 5);
        int s6 = __shfl(my, j + 6), s7 = __shfl(my, j + 7);
        uint v0 = sup[(size_t)s0 * 64 + lane];
        uint v1 = sup[(size_t)s1 * 64 + lane];
        uint v2 = sup[(size_t)s2 * 64 + lane];
        uint v3 = sup[(size_t)s3 * 64 + lane];
        uint v4 = sup[(size_t)s4 * 64 + lane];
        uint v5 = sup[(size_t)s5 * 64 + lane];
        uint v6 = sup[(size_t)s6 * 64 + lane];
        uint v7 = sup[(size_t)s7 * 64 + lane];
        ax += b2f_lo(v0) + b2f_lo(v1) + b2f_lo(v2) + b2f_lo(v3)
            + b2f_lo(v4) + b2f_lo(v5) + b2f_lo(v6) + b2f_lo(v7);
        ay += b2f_hi(v0) + b2f_hi(v1) + b2f_hi(v2) + b2f_hi(v3)
            + b2f_hi(v4) + b2f_hi(v5) + b2f_hi(v6) + b2f_hi(v7);
    }
    for (; j < n0; ++j) {
        int s = __shfl(my, j);
        uint v = sup[(size_t)s * 64 + lane];
        ax += b2f_lo(v); ay += b2f_hi(v);
    }
    for (int i = 64; i < cnt; ++i) {            // Poisson(16) tail: ~never
        int s = ssrc[off + i];
        uint v = sup[(size_t)s * 64 + lane];
        ax += b2f_lo(v); ay += b2f_hi(v);
    }
}

// layer-1: h1 = tanh(gather + b1), stored bf16
__global__ __launch_bounds__(256) void gather_tanh_k(
    const uint* __restrict__ sup, const int* __restrict__ offsets,
    const int* __restrict__ counts, const int* __restrict__ ssrc,
    const float* __restrict__ bias, uint* __restrict__ h1, int n_nodes) {
    int node = (blockIdx.x << 2) | (threadIdx.x >> 6);
    if (node >= n_nodes) return;
    int lane = threadIdx.x & 63;
    float ax, ay;
    gather_node(sup, offsets, counts, ssrc, bias, node, lane, ax, ay);
    uint o = ((uint)f2b(tanhf(ay)) << 16) | (uint)f2b(tanhf(ax));
    h1[(size_t)node * 64 + lane] = o;
}

// layer-2: gather + tanh + logmap0∘proj + segment-sum pool
__global__ __launch_bounds__(256) void gather_pool_k(
    const uint* __restrict__ sup, const int* __restrict__ offsets,
    const int* __restrict__ counts, const int* __restrict__ ssrc,
    const float* __restrict__ bias, const int* __restrict__ seg_ids,
    float* __restrict__ sums, int* __restrict__ seg_cnt, int n_nodes) {
    int node = (blockIdx.x << 2) | (threadIdx.x >> 6);
    if (node >= n_nodes) return;
    int lane = threadIdx.x & 63;
    float ax, ay;
    gather_node(sup, offsets, counts, ssrc, bias, node, lane, ax, ay);
    float hx = tanhf(ax), hy = tanhf(ay);
    float ss = hx * hx + hy * hy;
#pragma unroll
    for (int o = 32; o > 0; o >>= 1) ss += __shfl_xor(ss, o);
    double r = sqrt((double)fmaxf(ss, 1e-15f));
    double m = fmin(r, MAXNORM);
    float f = (float)(atanh(m) / r);            // logmap0(proj(h)) scale
    int seg = seg_ids[node];
    atomicAdd(&sums[seg * 128 + 2 * lane], hx * f);
    atomicAdd(&sums[seg * 128 + 2 * lane + 1], hy * f);
    if (lane == 0) atomicAdd(&seg_cnt[seg], 1);
}

// segment mean -> expmap0 -> proj
__global__ __launch_bounds__(64) void finalize_k(const float* __restrict__ sums,
                                                 const int* __restrict__ seg_cnt,
                                                 float* __restrict__ out) {
    int seg = blockIdx.x;
    int lane = threadIdx.x;
    float c = fmaxf((float)seg_cnt[seg], 1.0f);
    float ux = sums[seg * 128 + 2 * lane] / c;
    float uy = sums[seg * 128 + 2 * lane + 1] / c;
    float ss = ux * ux + uy * uy;
#pragma unroll
    for (int o = 32; o > 0; o >>= 1) ss += __shfl_xor(ss, o);
    double r = sqrt((double)fmaxf(ss, 1e-15f));
    double t = tanh(r);
    double fac = t / r;
    if (t > MAXNORM) fac = MAXNORM / r;
    float f = (float)fac;
    out[seg * 128 + 2 * lane] = ux * f;
    out[seg * 128 + 2 * lane + 1] = uy * f;
}

// ---------------------------------------------------------------------------
extern "C" void kernel_launch(void* const* d_in, const int* in_sizes, int n_in,
                              void* d_out, int out_size, void* d_ws, size_t ws_size,
                              hipStream_t stream) {
    const float* x   = (const float*)d_in[0];
    const int* src   = (const int*)d_in[1];
    const int* dst   = (const int*)d_in[2];
    const int* segid = (const int*)d_in[3];
    const float* W1  = (const float*)d_in[4];
    const float* b1  = (const float*)d_in[5];
    const float* W2  = (const float*)d_in[6];
    const float* b2  = (const float*)d_in[7];
    float* out       = (float*)d_out;

    const int N = in_sizes[3];          // 131072
    const int E = in_sizes[1];          // 2097152

    char* ws = (char*)d_ws;
    ushort* supA   = (ushort*)(ws);                      // N*128 bf16 = 32MB
    uint*   supA32 = (uint*)supA;
    ushort* h1     = (ushort*)(ws + 33554432);           // N*128 bf16 = 32MB
    uint*   h1u    = (uint*)h1;
    int* ssrc      = (int*)(ws + 67108864);              // E ints = 8MB
    int* counts    = (int*)(ws + 75497472);
    int* offsets   = (int*)(ws + 76021760);
    int* cursor    = (int*)(ws + 76546048);
    int* partials  = (int*)(ws + 77070336);
    float* sums    = (float*)(ws + 77071360);
    int* seg_cnt   = (int*)(ws + 77235200);
    ushort* w1t    = (ushort*)(ws + 77236480);           // 128x256 bf16
    ushort* w2t    = (ushort*)(ws + 77302016);           // 128x128 bf16

    hipMemsetAsync(counts, 0, (size_t)N * 4, stream);
    hipMemsetAsync(cursor, 0, (size_t)N * 4, stream);
    hipMemsetAsync(sums, 0, (size_t)NSEG * 128 * 4, stream);
    hipMemsetAsync(seg_cnt, 0, (size_t)NSEG * 4, stream);

    const int eblocks = (E + 255) / 256;
    const int nscan = N / 1024;

    prep_wt_k<<<192, 256, 0, stream>>>(W1, W2, w1t, w2t);

    count_edges_k<<<eblocks, 256, 0, stream>>>(dst, counts, E);
    scan_block_k<<<nscan, 256, 0, stream>>>(counts, offsets, partials);
    scan_partials_k<<<1, nscan, 0, stream>>>(partials, nscan);
    add_base_k<<<(N + 255) / 256, 256, 0, stream>>>(offsets, partials, N);
    fill_edges_k<<<eblocks, 256, 0, stream>>>(src, dst, offsets, cursor, ssrc, E);

    // layer 1
    gemm_k<true><<<N / 128, 256, 0, stream>>>(x, w1t, supA, IN_DIM);
    gather_tanh_k<<<N / 4, 256, 0, stream>>>(supA32, offsets, counts, ssrc, b1, h1u, N);

    // layer 2
    gemm_k<false><<<N / 128, 256, 0, stream>>>(h1, w2t, supA, HID);
    gather_pool_k<<<N / 4, 256, 0, stream>>>(supA32, offsets, counts, ssrc, b2, segid,
                                             sums, seg_cnt, N);

    finalize_k<<<NSEG, 64, 0, stream>>>(sums, seg_cnt, out);
}

// Round 3
// 594.411 us; speedup vs baseline: 1.3430x; 1.0137x over previous
//
#include <hip/hip_runtime.h>
#include <hip/hip_bf16.h>

#define IN_DIM 256
#define HID    128
#define NSEG   320
#define MAXNORM 0.99999

typedef short bf16x8 __attribute__((ext_vector_type(8)));
typedef float f32x4  __attribute__((ext_vector_type(4)));

static __device__ __forceinline__ ushort f2b(float f) {
    uint u = __builtin_bit_cast(uint, f);
    uint r = 0x7FFFu + ((u >> 16) & 1u);      // round-to-nearest-even
    return (ushort)((u + r) >> 16);
}
static __device__ __forceinline__ float b2f_lo(uint v) {
    return __builtin_bit_cast(float, v << 16);
}
static __device__ __forceinline__ float b2f_hi(uint v) {
    return __builtin_bit_cast(float, v & 0xFFFF0000u);
}

// ---------------------------------------------------------------------------
// CSR build: count -> exclusive scan -> fill (reused for both GCN layers)
// ---------------------------------------------------------------------------
__global__ void count_edges_k(const int* __restrict__ dst, int* __restrict__ counts, int n) {
    int e = blockIdx.x * 256 + threadIdx.x;
    if (e < n) atomicAdd(&counts[dst[e]], 1);
}

__global__ void scan_block_k(const int* __restrict__ in, int* __restrict__ out,
                             int* __restrict__ partials) {
    __shared__ int sh[256];
    int tid = threadIdx.x;
    int base = blockIdx.x * 1024 + tid * 4;
    int4 v = *(const int4*)&in[base];
    int s = v.x + v.y + v.z + v.w;
    sh[tid] = s;
    __syncthreads();
#pragma unroll
    for (int off = 1; off < 256; off <<= 1) {
        int t = (tid >= off) ? sh[tid - off] : 0;
        __syncthreads();
        sh[tid] += t;
        __syncthreads();
    }
    int excl = sh[tid] - s;
    int4 o;
    o.x = excl; o.y = excl + v.x; o.z = o.y + v.y; o.w = o.z + v.z;
    *(int4*)&out[base] = o;
    if (tid == 255) partials[blockIdx.x] = sh[255];
}

__global__ void scan_partials_k(int* __restrict__ partials, int n) {
    __shared__ int sh[1024];
    int tid = threadIdx.x;
    int v = (tid < n) ? partials[tid] : 0;
    sh[tid] = v;
    __syncthreads();
    for (int off = 1; off < blockDim.x; off <<= 1) {
        int t = (tid >= off) ? sh[tid - off] : 0;
        __syncthreads();
        sh[tid] += t;
        __syncthreads();
    }
    if (tid < n) partials[tid] = sh[tid] - v;
}

__global__ void add_base_k(int* __restrict__ offsets, const int* __restrict__ partials, int n) {
    int g = blockIdx.x * 256 + threadIdx.x;
    if (g < n) offsets[g] += partials[g >> 10];
}

__global__ void fill_edges_k(const int* __restrict__ src, const int* __restrict__ dst,
                             const int* __restrict__ offsets, int* __restrict__ cursor,
                             int* __restrict__ sorted_src, int n) {
    int e = blockIdx.x * 256 + threadIdx.x;
    if (e < n) {
        int d = dst[e];
        int pos = atomicAdd(&cursor[d], 1);
        sorted_src[offsets[d] + pos] = src[e];
    }
}

// ---------------------------------------------------------------------------
// W pre-transpose+convert: W[K][128] f32 -> WT[128][K] bf16 (both weights)
// ---------------------------------------------------------------------------
__global__ void prep_wt_k(const float* __restrict__ w1, const float* __restrict__ w2,
                          ushort* __restrict__ w1t, ushort* __restrict__ w2t) {
    int id = blockIdx.x * 256 + threadIdx.x;
    if (id < 32768) {                      // W1: 256x128 -> 128x256
        int n = id >> 8, k = id & 255;
        w1t[n * 256 + k] = f2b(w1[k * 128 + n]);
    } else {                               // W2: 128x128 -> 128x128
        int id2 = id - 32768;
        int n = id2 >> 7, k = id2 & 127;
        w2t[n * 128 + k] = f2b(w2[k * 128 + n]);
    }
}

// ---------------------------------------------------------------------------
// bf16 MFMA GEMM: C[M][128](bf16) = A[M][K] @ B[K][128]   (unchanged, verified)
// ---------------------------------------------------------------------------
template<bool AF32>
__global__ __launch_bounds__(256) void gemm_k(const void* __restrict__ Ap,
                                              const ushort* __restrict__ BT,
                                              ushort* __restrict__ C, int K) {
    __shared__ __align__(16) char As[16384];   // [128][64] bf16, swizzled
    __shared__ __align__(16) char Bs[16384];   // [128(n)][64(k)] bf16, swizzled
    const int tid = threadIdx.x;
    const int lane = tid & 63;
    const int wid = tid >> 6;
    const int wr = wid >> 1, wc = wid & 1;
    const int row0 = blockIdx.x * 128;
    f32x4 acc[4][4] = {};

    for (int k0 = 0; k0 < K; k0 += 64) {
        if (AF32) {
            const float* A = (const float*)Ap;
#pragma unroll
            for (int it = 0; it < 8; ++it) {
                int id = tid + it * 256;
                int r = id >> 4, c4 = (id & 15) * 4;
                float4 v = *(const float4*)&A[(size_t)(row0 + r) * K + k0 + c4];
                ushort4 h;
                h.x = f2b(v.x); h.y = f2b(v.y); h.z = f2b(v.z); h.w = f2b(v.w);
                *(ushort4*)(As + ((r * 128 + c4 * 2) ^ ((r & 7) << 4))) = h;
            }
        } else {
            const ushort* A = (const ushort*)Ap;
#pragma unroll
            for (int it = 0; it < 4; ++it) {
                int id = tid + it * 256;
                int r = id >> 3, c8 = (id & 7) * 8;
                bf16x8 v = *(const bf16x8*)&A[(size_t)(row0 + r) * K + k0 + c8];
                *(bf16x8*)(As + ((r * 128 + c8 * 2) ^ ((r & 7) << 4))) = v;
            }
        }
#pragma unroll
        for (int it = 0; it < 4; ++it) {
            int id = tid + it * 256;
            int n = id >> 3, c8 = (id & 7) * 8;
            bf16x8 v = *(const bf16x8*)&BT[(size_t)n * K + k0 + c8];
            *(bf16x8*)(Bs + ((n * 128 + c8 * 2) ^ ((n & 7) << 4))) = v;
        }
        __syncthreads();
#pragma unroll
        for (int kc = 0; kc < 2; ++kc) {
            bf16x8 af[4], bfr[4];
            int kb = (kc * 32 + (lane >> 4) * 8) * 2;
#pragma unroll
            for (int i = 0; i < 4; ++i) {
                int r = wr * 64 + i * 16 + (lane & 15);
                af[i] = *(const bf16x8*)(As + ((r * 128 + kb) ^ ((r & 7) << 4)));
                int n = wc * 64 + i * 16 + (lane & 15);
                bfr[i] = *(const bf16x8*)(Bs + ((n * 128 + kb) ^ ((n & 7) << 4)));
            }
#pragma unroll
            for (int i = 0; i < 4; ++i)
#pragma unroll
                for (int j = 0; j < 4; ++j)
                    acc[i][j] = __builtin_amdgcn_mfma_f32_16x16x32_bf16(
                        af[i], bfr[j], acc[i][j], 0, 0, 0);
        }
        __syncthreads();
    }
#pragma unroll
    for (int i = 0; i < 4; ++i)
#pragma unroll
        for (int j = 0; j < 4; ++j)
#pragma unroll
            for (int r = 0; r < 4; ++r) {
                int row = row0 + wr * 64 + i * 16 + (lane >> 4) * 4 + r;
                int col = wc * 64 + j * 16 + (lane & 15);
                C[(size_t)row * 128 + col] = f2b(acc[i][j][r]);
            }
}

// ---------------------------------------------------------------------------
// SCALARIZED gather core. node forced to SGPR via readfirstlane ->
// offsets/counts/edge-indices become s_loads, row base is SALU, row load is
// global_load_dword v, v_lane4, s[base]. 16 rows in flight per wave.
// ---------------------------------------------------------------------------
static __device__ __forceinline__ void gather_node(
    const uint* __restrict__ sup, const int* __restrict__ offsets,
    const int* __restrict__ counts, const int* __restrict__ ssrc,
    const float* __restrict__ bias, int node, int lane, float& ax, float& ay) {
    node = __builtin_amdgcn_readfirstlane(node);
    int off = __builtin_amdgcn_readfirstlane(offsets[node]);
    int cnt = __builtin_amdgcn_readfirstlane(counts[node]);
    float2 bv = *(const float2*)&bias[2 * lane];
    ax = bv.x;
    ay = bv.y;
    int j = 0;
    for (; j + 16 <= cnt; j += 16) {
        uint v[16];
#pragma unroll
        for (int t = 0; t < 16; ++t) {
            int s = ssrc[off + j + t];                // uniform -> s_load
            v[t] = sup[(size_t)s * 64 + lane];        // SGPR base + lane
        }
#pragma unroll
        for (int t = 0; t < 16; ++t) { ax += b2f_lo(v[t]); ay += b2f_hi(v[t]); }
    }
    for (; j + 4 <= cnt; j += 4) {
        uint v[4];
#pragma unroll
        for (int t = 0; t < 4; ++t) {
            int s = ssrc[off + j + t];
            v[t] = sup[(size_t)s * 64 + lane];
        }
#pragma unroll
        for (int t = 0; t < 4; ++t) { ax += b2f_lo(v[t]); ay += b2f_hi(v[t]); }
    }
    for (; j < cnt; ++j) {
        int s = ssrc[off + j];
        uint v = sup[(size_t)s * 64 + lane];
        ax += b2f_lo(v); ay += b2f_hi(v);
    }
}

// layer-1: h1 = tanh(gather + b1), stored bf16
__global__ __launch_bounds__(256) void gather_tanh_k(
    const uint* __restrict__ sup, const int* __restrict__ offsets,
    const int* __restrict__ counts, const int* __restrict__ ssrc,
    const float* __restrict__ bias, uint* __restrict__ h1, int n_nodes) {
    int node = (blockIdx.x << 2) | (threadIdx.x >> 6);
    if (node >= n_nodes) return;
    int lane = threadIdx.x & 63;
    float ax, ay;
    gather_node(sup, offsets, counts, ssrc, bias, node, lane, ax, ay);
    uint o = ((uint)f2b(tanhf(ay)) << 16) | (uint)f2b(tanhf(ax));
    h1[(size_t)node * 64 + lane] = o;
}

// layer-2: gather + tanh + logmap0∘proj + segment-sum pool
__global__ __launch_bounds__(256) void gather_pool_k(
    const uint* __restrict__ sup, const int* __restrict__ offsets,
    const int* __restrict__ counts, const int* __restrict__ ssrc,
    const float* __restrict__ bias, const int* __restrict__ seg_ids,
    float* __restrict__ sums, int* __restrict__ seg_cnt, int n_nodes) {
    int node = (blockIdx.x << 2) | (threadIdx.x >> 6);
    if (node >= n_nodes) return;
    int lane = threadIdx.x & 63;
    float ax, ay;
    gather_node(sup, offsets, counts, ssrc, bias, node, lane, ax, ay);
    float hx = tanhf(ax), hy = tanhf(ay);
    float ss = hx * hx + hy * hy;
#pragma unroll
    for (int o = 32; o > 0; o >>= 1) ss += __shfl_xor(ss, o);
    double r = sqrt((double)fmaxf(ss, 1e-15f));
    double m = fmin(r, MAXNORM);
    float f = (float)(atanh(m) / r);            // logmap0(proj(h)) scale
    int seg = seg_ids[node];
    atomicAdd(&sums[seg * 128 + 2 * lane], hx * f);
    atomicAdd(&sums[seg * 128 + 2 * lane + 1], hy * f);
    if (lane == 0) atomicAdd(&seg_cnt[seg], 1);
}

// segment mean -> expmap0 -> proj
__global__ __launch_bounds__(64) void finalize_k(const float* __restrict__ sums,
                                                 const int* __restrict__ seg_cnt,
                                                 float* __restrict__ out) {
    int seg = blockIdx.x;
    int lane = threadIdx.x;
    float c = fmaxf((float)seg_cnt[seg], 1.0f);
    float ux = sums[seg * 128 + 2 * lane] / c;
    float uy = sums[seg * 128 + 2 * lane + 1] / c;
    float ss = ux * ux + uy * uy;
#pragma unroll
    for (int o = 32; o > 0; o >>= 1) ss += __shfl_xor(ss, o);
    double r = sqrt((double)fmaxf(ss, 1e-15f));
    double t = tanh(r);
    double fac = t / r;
    if (t > MAXNORM) fac = MAXNORM / r;
    float f = (float)fac;
    out[seg * 128 + 2 * lane] = ux * f;
    out[seg * 128 + 2 * lane + 1] = uy * f;
}

// ---------------------------------------------------------------------------
extern "C" void kernel_launch(void* const* d_in, const int* in_sizes, int n_in,
                              void* d_out, int out_size, void* d_ws, size_t ws_size,
                              hipStream_t stream) {
    const float* x   = (const float*)d_in[0];
    const int* src   = (const int*)d_in[1];
    const int* dst   = (const int*)d_in[2];
    const int* segid = (const int*)d_in[3];
    const float* W1  = (const float*)d_in[4];
    const float* b1  = (const float*)d_in[5];
    const float* W2  = (const float*)d_in[6];
    const float* b2  = (const float*)d_in[7];
    float* out       = (float*)d_out;

    const int N = in_sizes[3];          // 131072
    const int E = in_sizes[1];          // 2097152

    char* ws = (char*)d_ws;
    ushort* supA   = (ushort*)(ws);                      // N*128 bf16 = 32MB
    uint*   supA32 = (uint*)supA;
    ushort* h1     = (ushort*)(ws + 33554432);           // N*128 bf16 = 32MB
    uint*   h1u    = (uint*)h1;
    int* ssrc      = (int*)(ws + 67108864);              // E ints = 8MB
    int* counts    = (int*)(ws + 75497472);
    int* offsets   = (int*)(ws + 76021760);
    int* cursor    = (int*)(ws + 76546048);
    int* partials  = (int*)(ws + 77070336);
    float* sums    = (float*)(ws + 77071360);
    int* seg_cnt   = (int*)(ws + 77235200);
    ushort* w1t    = (ushort*)(ws + 77236480);           // 128x256 bf16
    ushort* w2t    = (ushort*)(ws + 77302016);           // 128x128 bf16

    hipMemsetAsync(counts, 0, (size_t)N * 4, stream);
    hipMemsetAsync(cursor, 0, (size_t)N * 4, stream);
    hipMemsetAsync(sums, 0, (size_t)NSEG * 128 * 4, stream);
    hipMemsetAsync(seg_cnt, 0, (size_t)NSEG * 4, stream);

    const int eblocks = (E + 255) / 256;
    const int nscan = N / 1024;

    prep_wt_k<<<192, 256, 0, stream>>>(W1, W2, w1t, w2t);

    count_edges_k<<<eblocks, 256, 0, stream>>>(dst, counts, E);
    scan_block_k<<<nscan, 256, 0, stream>>>(counts, offsets, partials);
    scan_partials_k<<<1, nscan, 0, stream>>>(partials, nscan);
    add_base_k<<<(N + 255) / 256, 256, 0, stream>>>(offsets, partials, N);
    fill_edges_k<<<eblocks, 256, 0, stream>>>(src, dst, offsets, cursor, ssrc, E);

    // layer 1
    gemm_k<true><<<N / 128, 256, 0, stream>>>(x, w1t, supA, IN_DIM);
    gather_tanh_k<<<N / 4, 256, 0, stream>>>(supA32, offsets, counts, ssrc, b1, h1u, N);

    // layer 2
    gemm_k<false><<<N / 128, 256, 0, stream>>>(h1, w2t, supA, HID);
    gather_pool_k<<<N / 4, 256, 0, stream>>>(supA32, offsets, counts, ssrc, b2, segid,
                                             sums, seg_cnt, N);

    finalize_k<<<NSEG, 64, 0, stream>>>(sums, seg_cnt, out);
}